// Round 7
// baseline (913.828 us; speedup 1.0000x reference)
//
#include <hip/hip_runtime.h>
#include <stdint.h>

typedef __bf16 bf16x8 __attribute__((ext_vector_type(8)));
typedef float floatx4 __attribute__((ext_vector_type(4)));

__device__ __forceinline__ void gload_lds16(const void* g, void* l) {
    __builtin_amdgcn_global_load_lds((const __attribute__((address_space(1))) void*)g,
                                     (__attribute__((address_space(3))) void*)l, 16, 0, 0);
}

__device__ __forceinline__ uint16_t f2bf(float f) {
    uint32_t u = __float_as_uint(f);
    u += 0x7fff + ((u >> 16) & 1);   // RNE
    return (uint16_t)(u >> 16);
}
__device__ __forceinline__ uint32_t f2bf2(float lo, float hi) {
    return (uint32_t)f2bf(lo) | ((uint32_t)f2bf(hi) << 16);
}

// ---- cross-block sync (all 768 blocks co-resident by construction) --------
__device__ __forceinline__ void bump(int* p) {
    __syncthreads();                      // block stores drained (vmcnt0 at barrier)
    if (threadIdx.x == 0)
        __hip_atomic_fetch_add(p, 1, __ATOMIC_RELEASE, __HIP_MEMORY_SCOPE_AGENT);
}
__device__ __forceinline__ void wait_ge(int* p, int target) {
    if (threadIdx.x == 0)
        while (__hip_atomic_load(p, __ATOMIC_ACQUIRE, __HIP_MEMORY_SCOPE_AGENT) < target)
            __builtin_amdgcn_s_sleep(2);
    __syncthreads();
}

// ---- fused normalize_adj + sparse row gather ------------------------------
struct AmulSM {
    float vv[256];
    int   jj[256];
    float part[4];
    int   wcnt[4];
    int   woff[4];
    float sinv;
    int   n0;
};

union MegaSM {
    uint16_t u16[8192];     // conv As[4096]+Bs[4096]; g64 As[2048]+Bs[2048]
    float    wbuf[6144];    // wT staging (24 KB -> LDS block size, 3/CU ok)
    float    tile[64][65];  // transposes
    AmulSM   am;
};

__device__ __forceinline__ void amul_body(const float* __restrict__ adj,
                                          const float* __restrict__ H,
                                          uint16_t* __restrict__ outp,
                                          int b, int i, int tid, AmulSM* sm)
{
    const float* A = adj + ((size_t)b << 16);
    float aij = A[(i << 8) + tid];
    float aji = A[(tid << 8) + i];
    float v = fmaxf(aij, aji);
    if (tid == i) v += 1.0f;

    float s = v;
    #pragma unroll
    for (int off = 32; off > 0; off >>= 1) s += __shfl_down(s, off);

    bool pred = v != 0.0f;
    unsigned long long m = __ballot(pred);
    int wid = tid >> 6;
    if ((tid & 63) == 0) { sm->part[wid] = s; sm->wcnt[wid] = (int)__popcll(m); }
    __syncthreads();
    if (tid == 0) {
        float t = sm->part[0] + sm->part[1] + sm->part[2] + sm->part[3];
        sm->sinv = t > 0.0f ? 1.0f / t : 0.0f;
        int o = 0;
        #pragma unroll
        for (int w = 0; w < 4; ++w) { sm->woff[w] = o; o += sm->wcnt[w]; }
        sm->n0 = o;
    }
    __syncthreads();
    if (pred) {
        int pos = sm->woff[wid] + (int)__popcll(m & ((1ull << (tid & 63)) - 1ull));
        sm->vv[pos] = v * sm->sinv;
        sm->jj[pos] = tid;
    }
    __syncthreads();

    const int n0 = sm->n0;
    const int f0 = tid * 8;
    const float* Hb = H + (((size_t)b) << 8) * 2048;
    float acc[8] = {};
    for (int c = 0; c < n0; ++c) {
        float av = sm->vv[c];
        const float* hp = Hb + (size_t)sm->jj[c] * 2048 + f0;
        float4 p = *(const float4*)hp;
        float4 q = *(const float4*)(hp + 4);
        acc[0] += av * p.x; acc[1] += av * p.y; acc[2] += av * p.z; acc[3] += av * p.w;
        acc[4] += av * q.x; acc[5] += av * q.y; acc[6] += av * q.z; acc[7] += av * q.w;
    }
    uint4 o;
    o.x = f2bf2(acc[0], acc[1]);
    o.y = f2bf2(acc[2], acc[3]);
    o.z = f2bf2(acc[4], acc[5]);
    o.w = f2bf2(acc[6], acc[7]);
    *(uint4*)(outp + (((size_t)b << 8) + i) * 2048 + f0) = o;
}

__device__ __forceinline__ void amul_swizzle(int id, int& b, int& i) {
    int x = id & 7, g = id >> 3;        // XCD = id % 8 (round-robin, verified R6)
    b = x >> 1;
    i = ((x & 1) << 7) + g;
}

// ---- 64x64 GEMM tile: C = A @ BT^T + bias (+relu), K=2048 -----------------
template<bool RELU>
__device__ __forceinline__ void g64_tile(MegaSM* sm, const uint16_t* __restrict__ A,
                                         const uint16_t* __restrict__ BT,
                                         float* __restrict__ C, const float* __restrict__ bias,
                                         int id)
{
    uint16_t* As = sm->u16;
    uint16_t* Bs = sm->u16 + 2048;
    const int tid  = threadIdx.x;
    const int xc   = id & 7;
    const int g    = id >> 3;           // 0..63
    const int rt   = (g & 15) * 64;
    const int ct   = (4 * xc + (g >> 4)) * 64;
    const int lane = tid & 63;
    const int wave = tid >> 6;
    const int wm   = (wave >> 1) * 32;
    const int wn   = (wave & 1) * 32;
    const int lm   = lane & 15;
    const int kq   = (lane >> 4) * 8;
    const int srow  = tid >> 2;
    const int skcol = (tid & 3) * 8;

    const size_t abase = (size_t)(rt + srow) * 2048 + skcol;
    const size_t bbase = (size_t)(ct + srow) * 2048 + skcol;

    floatx4 acc[2][2] = {};

    for (int k0 = 0; k0 < 2048; k0 += 32) {
        gload_lds16(A  + abase + k0, &As[tid * 8]);
        gload_lds16(BT + bbase + k0, &Bs[tid * 8]);
        __syncthreads();

        bf16x8 af[2], bfr[2];
        #pragma unroll
        for (int mt = 0; mt < 2; ++mt)
            af[mt] = *(const bf16x8*)&As[(wm + mt * 16 + lm) * 32 + kq];
        #pragma unroll
        for (int nt = 0; nt < 2; ++nt)
            bfr[nt] = *(const bf16x8*)&Bs[(wn + nt * 16 + lm) * 32 + kq];
        #pragma unroll
        for (int mt = 0; mt < 2; ++mt)
            #pragma unroll
            for (int nt = 0; nt < 2; ++nt)
                acc[mt][nt] = __builtin_amdgcn_mfma_f32_16x16x32_bf16(af[mt], bfr[nt], acc[mt][nt], 0, 0, 0);
        __syncthreads();
    }

    const int lq = lane >> 4;
    #pragma unroll
    for (int mt = 0; mt < 2; ++mt)
        #pragma unroll
        for (int nt = 0; nt < 2; ++nt) {
            int col = ct + wn + nt * 16 + lm;
            float bv = bias[col];
            #pragma unroll
            for (int r = 0; r < 4; ++r) {
                int row = rt + wm + mt * 16 + lq * 4 + r;
                float v = acc[mt][nt][r] + bv;
                if (RELU) v = fmaxf(v, 0.0f);
                C[(size_t)row * 2048 + col] = v;
            }
        }
}

// ---- params ---------------------------------------------------------------
struct KP {
    const float *x, *nodes, *adj, *conv_w, *conv_b, *W1, *b1, *W2, *b2;
    uint16_t *xpad, *wmT, *W1T, *W2T, *gbf, *ahb;
    float *h, *feats, *out2;
    int *cnt0, *cntH, *cnt2;
};

// phase-0 item ranges
#define IT_AM 1024
#define IT_W  3072
#define IT_T1 4096
#define IT_T2 5120
#define IT_N  17456   // + 12336 pad_x items (float4)

// ---- the single mega-kernel: grid MUST be 768 (3 blocks/CU co-resident) ---
__global__ __launch_bounds__(256, 3) void k_mega(KP p)
{
    __shared__ MegaSM sm;
    const int bid  = blockIdx.x;
    const int tid  = threadIdx.x;
    const int lane = tid & 63;
    const int wave = tid >> 6;
    const int lm   = lane & 15;
    const int kq   = (lane >> 4) * 8;
    const int lq   = lane >> 4;
    const int srow  = tid >> 2;
    const int skcol = (tid & 3) * 8;

    // ================= phase 0: all input-only prep ========================
    for (int item = bid; item < IT_N; item += 768) {
        if (item < IT_AM) {
            int b, i; amul_swizzle(item, b, i);
            amul_body(p.adj, p.nodes, p.gbf, b, i, tid, &sm.am);    // gbf = a@nodes
        } else if (item < IT_W) {
            // conv_w [o][i][h] -> wmT [o][h*2048+i] bf16
            int o = item - IT_AM;
            const float* src = p.conv_w + (size_t)o * 6144;
            uint16_t*    dst = p.wmT + (size_t)o * 6144;
            #pragma unroll
            for (int it = 0; it < 24; ++it)
                sm.wbuf[it * 256 + tid] = src[it * 256 + tid];
            __syncthreads();
            #pragma unroll
            for (int hh = 0; hh < 3; ++hh)
                #pragma unroll
                for (int c = 0; c < 8; ++c) {
                    int i = c * 256 + tid;
                    dst[hh * 2048 + i] = f2bf(sm.wbuf[i * 3 + hh]);  // stride-3: conflict-free
                }
        } else if (item < IT_T2) {
            // W1/W2 [2048][2048] -> bf16 transpose
            int t  = item - ((item < IT_T1) ? IT_W : IT_T1);
            const float* src = (item < IT_T1) ? p.W1 : p.W2;
            uint16_t*    dst = (item < IT_T1) ? p.W1T : p.W2T;
            int by = (t >> 5) & 31;
            int bx = t & 31;
            int tx = tid & 63, ty = tid >> 6;
            for (int rr = ty; rr < 64; rr += 4)
                sm.tile[rr][tx] = src[(size_t)(by * 64 + rr) * 2048 + bx * 64 + tx];
            __syncthreads();
            for (int rr = ty; rr < 64; rr += 4)
                dst[(size_t)(bx * 64 + rr) * 2048 + by * 64 + tx] = f2bf(sm.tile[tx][rr]);
        } else {
            // x [12,512,2048] f32 -> xpad [12,514,2048] bf16, 4 elems/thread
            int idx4 = (item - IT_T2) * 256 + tid;     // < 3,158,016
            int ch4  = idx4 & 511;
            int tmp  = idx4 >> 9;                      // b*514 + tt
            int b    = tmp / 514;
            int tt   = tmp - b * 514;
            float4 v = {0.0f, 0.0f, 0.0f, 0.0f};
            if (tt >= 1 && tt <= 512)
                v = *(const float4*)(p.x + ((size_t)(b * 512 + tt - 1) << 11) + ch4 * 4);
            uint2 o = { f2bf2(v.x, v.y), f2bf2(v.z, v.w) };
            ((uint2*)p.xpad)[idx4] = o;
        }
        __syncthreads();
    }
    bump(p.cnt0);
    wait_ge(p.cnt0, 768);       // grid barrier: xpad/wmT/W1T/W2T/gbf ready

    // ================= phase 1: conv GEMM, one 128x128 tile per block ======
    {
        uint16_t* As = sm.u16;
        uint16_t* Bs = sm.u16 + 4096;
        const int xc = bid & 7;
        const int g  = bid >> 3;            // 0..95
        const int rt = (12 * (xc >> 1) + (g % 12)) * 128;
        const int ct = (8 * (xc & 1) + (g / 12)) * 128;
        const int wm = (wave >> 1) * 64;
        const int wn = (wave & 1) * 64;

        floatx4 acc[4][4] = {};

        for (int k0 = 0; k0 < 6144; k0 += 32) {
            #pragma unroll
            for (int ii = 0; ii < 2; ++ii) {
                int row = ii * 64 + srow;
                int r  = rt + row;
                int b  = r >> 9;
                int t  = r & 511;
                int kk = k0 + skcol;
                int hh = kk >> 11;
                int ic = kk & 2047;
                gload_lds16(p.xpad + ((size_t)(b * 514 + t + hh) << 11) + ic,
                            &As[ii * 2048 + tid * 8]);
                gload_lds16(p.wmT + (size_t)(ct + row) * 6144 + k0 + skcol,
                            &Bs[ii * 2048 + tid * 8]);
            }
            __syncthreads();

            bf16x8 af[4], bfr[4];
            #pragma unroll
            for (int mt = 0; mt < 4; ++mt)
                af[mt] = *(const bf16x8*)&As[(wm + mt * 16 + lm) * 32 + kq];
            #pragma unroll
            for (int nt = 0; nt < 4; ++nt)
                bfr[nt] = *(const bf16x8*)&Bs[(wn + nt * 16 + lm) * 32 + kq];
            #pragma unroll
            for (int mt = 0; mt < 4; ++mt)
                #pragma unroll
                for (int nt = 0; nt < 4; ++nt)
                    acc[mt][nt] = __builtin_amdgcn_mfma_f32_16x16x32_bf16(af[mt], bfr[nt], acc[mt][nt], 0, 0, 0);
            __syncthreads();
        }

        #pragma unroll
        for (int mt = 0; mt < 4; ++mt)
            #pragma unroll
            for (int nt = 0; nt < 4; ++nt) {
                int col = ct + wn + nt * 16 + lm;
                float bv = p.conv_b[col];
                #pragma unroll
                for (int r = 0; r < 4; ++r) {
                    int row = rt + wm + mt * 16 + lq * 4 + r;
                    p.feats[(size_t)row * 2048 + col] = fmaxf(acc[mt][nt][r] + bv, 0.0f);
                }
            }
    }

    // ================= phase 2: GCN tail, flag-ordered =====================
    // g64#1: h = relu(gbf @ W1T^T + b1); tile id = bid for bid<512
    if (bid < 512) {
        g64_tile<true>(&sm, p.gbf, p.W1T, p.h, p.b1, bid);
        bump(&p.cntH[((bid >> 3) & 15) >> 2]);      // batch = rt_tile>>2, 128 tiles/batch
    }
    // amul#2: ahb = a @ h; row = bid (+768 for bid<256)
    {
        wait_ge(&p.cntH[bid >> 8], 128);
        amul_body(p.adj, p.h, p.ahb, bid >> 8, bid & 255, tid, &sm.am);
        bump(&p.cnt2[bid >> 6]);
    }
    if (bid < 256) {
        wait_ge(&p.cntH[3], 128);
        amul_body(p.adj, p.h, p.ahb, 3, bid, tid, &sm.am);
        bump(&p.cnt2[12 + (bid >> 6)]);
    }
    // g64#2: out2 = ahb @ W2T^T + b2; tile id = bid-256 for bid>=256
    if (bid >= 256) {
        int id = bid - 256;
        wait_ge(&p.cnt2[(id >> 3) & 15], 64);       // A rows [rt, rt+64) ready
        g64_tile<false>(&sm, p.ahb, p.W2T, p.out2, p.b2, id);
    }
}

// ---- launch ---------------------------------------------------------------

extern "C" void kernel_launch(void* const* d_in, const int* in_sizes, int n_in,
                              void* d_out, int out_size, void* d_ws, size_t ws_size,
                              hipStream_t stream)
{
    char* ws = (char*)d_ws;
    KP p;
    p.x      = (const float*)d_in[0];
    p.nodes  = (const float*)d_in[1];
    p.adj    = (const float*)d_in[2];
    p.conv_w = (const float*)d_in[3];
    p.conv_b = (const float*)d_in[4];
    p.W1     = (const float*)d_in[5];
    p.b1     = (const float*)d_in[6];
    p.W2     = (const float*)d_in[7];
    p.b2     = (const float*)d_in[8];
    p.xpad   = (uint16_t*)(ws);                 // 25,288,704
    p.wmT    = (uint16_t*)(ws + 25288704);      // 25,165,824
    p.W1T    = (uint16_t*)(ws + 50454528);      // 8,388,608
    p.W2T    = (uint16_t*)(ws + 58843136);      // 8,388,608
    p.gbf    = (uint16_t*)(ws + 67231744);      // 4,194,304
    p.h      = (float*)   (ws + 71426048);      // 8,388,608
    p.ahb    = (uint16_t*)(ws + 79814656);      // 4,194,304
    p.cnt0   = (int*)     (ws + 84008960);      // counters (128 B)
    p.cntH   = p.cnt0 + 1;
    p.cnt2   = p.cnt0 + 5;
    p.feats  = (float*)d_out;
    p.out2   = (float*)d_out + 12582912;

    hipMemsetAsync(p.cnt0, 0, 128, stream);
    k_mega<<<768, 256, 0, stream>>>(p);
}

// Round 8
// 411.935 us; speedup vs baseline: 2.2184x; 2.2184x over previous
//
#include <hip/hip_runtime.h>
#include <stdint.h>

typedef __bf16 bf16x8 __attribute__((ext_vector_type(8)));
typedef float floatx4 __attribute__((ext_vector_type(4)));

__device__ __forceinline__ void gload_lds16(const void* g, void* l) {
    __builtin_amdgcn_global_load_lds((const __attribute__((address_space(1))) void*)g,
                                     (__attribute__((address_space(3))) void*)l, 16, 0, 0);
}

__device__ __forceinline__ uint16_t f2bf(float f) {
    uint32_t u = __float_as_uint(f);
    u += 0x7fff + ((u >> 16) & 1);   // RNE
    return (uint16_t)(u >> 16);
}
__device__ __forceinline__ uint32_t f2bf2(float lo, float hi) {
    return (uint32_t)f2bf(lo) | ((uint32_t)f2bf(hi) << 16);
}

// ---- fused normalize_adj + sparse row gather ------------------------------
struct AmulSM {
    float vv[256];
    int   jj[256];
    float part[4];
    int   wcnt[4];
    int   woff[4];
    float sinv;
    int   n0;
};

__device__ __forceinline__ void amul_body(const float* __restrict__ adj,
                                          const float* __restrict__ H,
                                          uint16_t* __restrict__ outp,
                                          int b, int i, int tid, AmulSM* sm)
{
    const float* A = adj + ((size_t)b << 16);
    float aij = A[(i << 8) + tid];
    float aji = A[(tid << 8) + i];
    float v = fmaxf(aij, aji);
    if (tid == i) v += 1.0f;

    float s = v;
    #pragma unroll
    for (int off = 32; off > 0; off >>= 1) s += __shfl_down(s, off);

    bool pred = v != 0.0f;
    unsigned long long m = __ballot(pred);
    int wid = tid >> 6;
    if ((tid & 63) == 0) { sm->part[wid] = s; sm->wcnt[wid] = (int)__popcll(m); }
    __syncthreads();
    if (tid == 0) {
        float t = sm->part[0] + sm->part[1] + sm->part[2] + sm->part[3];
        sm->sinv = t > 0.0f ? 1.0f / t : 0.0f;
        int o = 0;
        #pragma unroll
        for (int w = 0; w < 4; ++w) { sm->woff[w] = o; o += sm->wcnt[w]; }
        sm->n0 = o;
    }
    __syncthreads();
    if (pred) {
        int pos = sm->woff[wid] + (int)__popcll(m & ((1ull << (tid & 63)) - 1ull));
        sm->vv[pos] = v * sm->sinv;
        sm->jj[pos] = tid;
    }
    __syncthreads();

    const int n0 = sm->n0;
    const int f0 = tid * 8;
    const float* Hb = H + (((size_t)b) << 8) * 2048;
    float acc[8] = {};
    for (int c = 0; c < n0; ++c) {
        float av = sm->vv[c];
        const float* hp = Hb + (size_t)sm->jj[c] * 2048 + f0;
        float4 p = *(const float4*)hp;
        float4 q = *(const float4*)(hp + 4);
        acc[0] += av * p.x; acc[1] += av * p.y; acc[2] += av * p.z; acc[3] += av * p.w;
        acc[4] += av * q.x; acc[5] += av * q.y; acc[6] += av * q.z; acc[7] += av * q.w;
    }
    uint4 o;
    o.x = f2bf2(acc[0], acc[1]);
    o.y = f2bf2(acc[2], acc[3]);
    o.z = f2bf2(acc[4], acc[5]);
    o.w = f2bf2(acc[6], acc[7]);
    *(uint4*)(outp + (((size_t)b << 8) + i) * 2048 + f0) = o;
}

// XCD-swizzled (b,i): XCD x (=bid%8) keeps one batch's H (2MB) L2-resident
__device__ __forceinline__ void amul_swizzle(int bid, int& b, int& i) {
    int x = bid & 7, g = bid >> 3;
    b = x >> 1;
    i = ((x & 1) << 7) + g;
}

// ---- dispatch 1: amul#1 | wT | W1/W2-transpose | pad_x (inputs only) ------
//   [0, 1024)        amul#1: gbf = a @ nodes (bf16)
//   [1024, 3072)     conv_w -> wT bf16
//   [3072, 5120)     W1/W2 -> bf16 transpose
//   [5120, 17456)    pad_x (float4, 12336 blocks)
#define PR_AM 1024
#define PR_W  3072
#define PR_T  5120
#define PR_N  17456

__global__ __launch_bounds__(256)
void k_prep(const float* __restrict__ x, uint16_t* __restrict__ xpad,
            const float* __restrict__ w, uint16_t* __restrict__ wT,
            const float* __restrict__ W1, const float* __restrict__ W2,
            uint16_t* __restrict__ W1T, uint16_t* __restrict__ W2T,
            const float* __restrict__ adj, const float* __restrict__ nodes,
            uint16_t* __restrict__ gbf)
{
    __shared__ union {
        float  wbuf[6144];
        float  tile[64][65];
        AmulSM am;
    } sm;
    const int bid = blockIdx.x;
    const int tid = threadIdx.x;

    if (bid < PR_AM) {
        int b, i; amul_swizzle(bid, b, i);
        amul_body(adj, nodes, gbf, b, i, tid, &sm.am);
    } else if (bid < PR_W) {
        // conv_w [o][i][h] -> wT [o][h*2048+i] bf16 (LDS-staged)
        int o = bid - PR_AM;
        const float* src = w + (size_t)o * 6144;
        uint16_t*    dst = wT + (size_t)o * 6144;
        #pragma unroll
        for (int it = 0; it < 24; ++it)
            sm.wbuf[it * 256 + tid] = src[it * 256 + tid];
        __syncthreads();
        #pragma unroll
        for (int h = 0; h < 3; ++h)
            #pragma unroll
            for (int c = 0; c < 8; ++c) {
                int i = c * 256 + tid;
                dst[h * 2048 + i] = f2bf(sm.wbuf[i * 3 + h]);   // stride-3: conflict-free
            }
    } else if (bid < PR_T) {
        // W1/W2 [2048][2048] -> bf16 transpose
        int t  = bid - PR_W;
        int z  = t >> 10;
        int by = (t >> 5) & 31;
        int bx = t & 31;
        const float* src = z ? W2 : W1;
        uint16_t*    dst = z ? W2T : W1T;
        int tx = tid & 63, ty = tid >> 6;
        for (int rr = ty; rr < 64; rr += 4)
            sm.tile[rr][tx] = src[(size_t)(by * 64 + rr) * 2048 + bx * 64 + tx];
        __syncthreads();
        for (int rr = ty; rr < 64; rr += 4)
            dst[(size_t)(bx * 64 + rr) * 2048 + by * 64 + tx] = f2bf(sm.tile[tx][rr]);
    } else {
        // x [12,512,2048] f32 -> xpad [12,514,2048] bf16, 4 elems/thread
        int idx4 = (bid - PR_T) * 256 + tid;       // < 3,158,016
        int ch4  = idx4 & 511;
        int tmp  = idx4 >> 9;                      // b*514 + tt
        int b    = tmp / 514;
        int tt   = tmp - b * 514;
        float4 v = {0.0f, 0.0f, 0.0f, 0.0f};
        if (tt >= 1 && tt <= 512)
            v = *(const float4*)(x + ((size_t)(b * 512 + tt - 1) << 11) + ch4 * 4);
        uint2 o = { f2bf2(v.x, v.y), f2bf2(v.z, v.w) };
        ((uint2*)xpad)[idx4] = o;
    }
}

// ---- 64x64 GEMM tile body, BK=64, LDS split-half layout [s][64][32] -------
// As/Bs each 4096 u16. Staging: 2 passes/matrix, pass p fills half s=p
// (all 64 rows, cols p*32..p*32+31); LDS dest = p*2048 + tid*8 (contiguous).
template<bool RELU>
__device__ __forceinline__ void g64_tile(uint16_t* As, uint16_t* Bs,
                                         const uint16_t* __restrict__ A,
                                         const uint16_t* __restrict__ BT,
                                         float* __restrict__ C, const float* __restrict__ bias,
                                         int rt, int ct)
{
    const int tid  = threadIdx.x;
    const int lane = tid & 63;
    const int wave = tid >> 6;
    const int wm   = (wave >> 1) * 32;
    const int wn   = (wave & 1) * 32;
    const int lm   = lane & 15;
    const int kq   = (lane >> 4) * 8;
    const int sr   = tid >> 2;           // 0..63 (row)
    const int sc   = (tid & 3) * 8;      // 0..24 (col within half)

    const size_t abase = (size_t)(rt + sr) * 2048 + sc;
    const size_t bbase = (size_t)(ct + sr) * 2048 + sc;

    floatx4 acc[2][2] = {};

    for (int k0 = 0; k0 < 2048; k0 += 64) {
        #pragma unroll
        for (int p = 0; p < 2; ++p) {
            gload_lds16(A  + abase + k0 + p * 32, &As[p * 2048 + tid * 8]);
            gload_lds16(BT + bbase + k0 + p * 32, &Bs[p * 2048 + tid * 8]);
        }
        __syncthreads();

        #pragma unroll
        for (int s = 0; s < 2; ++s) {
            bf16x8 af[2], bfr[2];
            #pragma unroll
            for (int mt = 0; mt < 2; ++mt)
                af[mt] = *(const bf16x8*)&As[s * 2048 + (wm + mt * 16 + lm) * 32 + kq];
            #pragma unroll
            for (int nt = 0; nt < 2; ++nt)
                bfr[nt] = *(const bf16x8*)&Bs[s * 2048 + (wn + nt * 16 + lm) * 32 + kq];
            #pragma unroll
            for (int mt = 0; mt < 2; ++mt)
                #pragma unroll
                for (int nt = 0; nt < 2; ++nt)
                    acc[mt][nt] = __builtin_amdgcn_mfma_f32_16x16x32_bf16(af[mt], bfr[nt], acc[mt][nt], 0, 0, 0);
        }
        __syncthreads();
    }

    const int lq = lane >> 4;
    #pragma unroll
    for (int mt = 0; mt < 2; ++mt)
        #pragma unroll
        for (int nt = 0; nt < 2; ++nt) {
            int col = ct + wn + nt * 16 + lm;
            float bv = bias[col];
            #pragma unroll
            for (int r = 0; r < 4; ++r) {
                int row = rt + wm + mt * 16 + lq * 4 + r;
                float v = acc[mt][nt][r] + bv;
                if (RELU) v = fmaxf(v, 0.0f);
                C[(size_t)row * 2048 + col] = v;
            }
        }
}

// ---- dispatch 2: conv GEMM (768 blocks) || gemm64#1 (512 blocks) ----------
// conv: 128x128 tile, BK=64, LDS [s][128][32] per matrix (8192 u16 each).
__global__ __launch_bounds__(256)
void k_big(const uint16_t* __restrict__ xpad, const uint16_t* __restrict__ wmT,
           float* __restrict__ feats, const float* __restrict__ conv_b,
           const uint16_t* __restrict__ gbf, const uint16_t* __restrict__ W1T,
           float* __restrict__ h, const float* __restrict__ b1)
{
    __shared__ __align__(16) uint16_t lds[16384];   // conv As[8192]+Bs[8192]; g64 uses 8192
    const int bid  = blockIdx.x;
    const int tid  = threadIdx.x;
    const int lane = tid & 63;
    const int wave = tid >> 6;
    const int lm   = lane & 15;
    const int kq   = (lane >> 4) * 8;
    const int lq   = lane >> 4;

    if (bid < 768) {
        // ---------------- conv GEMM 128x128, K=6144, BK=64, XCD-swizzled ---
        uint16_t* As = lds;
        uint16_t* Bs = lds + 8192;
        const int xc = bid & 7;
        const int g  = bid >> 3;            // 0..95
        const int rt = (12 * (xc >> 1) + (g % 12)) * 128;
        const int ct = (8 * (xc & 1) + (g / 12)) * 128;
        const int wm = (wave >> 1) * 64;
        const int wn = (wave & 1) * 64;

        // staging: pass p in 0..3: s=p>>1, row=(p&1)*64 + tid>>2, col=s*32+(tid&3)*8
        const int sr = tid >> 2;            // 0..63
        const int sc = (tid & 3) * 8;       // 0..24
        // im2col row bases for the two row-halves
        size_t arow[2]; size_t brow[2];
        #pragma unroll
        for (int rh = 0; rh < 2; ++rh) {
            int r = rt + rh * 64 + sr;
            int b = r >> 9;
            int t = r & 511;
            arow[rh] = ((size_t)(b * 514 + t) << 11);
            brow[rh] = (size_t)(ct + rh * 64 + sr) * 6144;
        }

        floatx4 acc[4][4] = {};

        for (int k0 = 0; k0 < 6144; k0 += 64) {
            // hh constant over the whole 64-chunk (k0 % 64 == 0, 2048 % 64 == 0)
            const int hh = k0 >> 11;
            const int icb = (k0 & 2047) + sc;
            #pragma unroll
            for (int p = 0; p < 4; ++p) {
                const int s  = p >> 1;
                const int rh = p & 1;
                gload_lds16(xpad + arow[rh] + ((size_t)hh << 11) + icb + s * 32,
                            &As[p * 2048 + tid * 8]);
                gload_lds16(wmT + brow[rh] + k0 + sc + s * 32,
                            &Bs[p * 2048 + tid * 8]);
            }
            __syncthreads();

            #pragma unroll
            for (int s = 0; s < 2; ++s) {
                bf16x8 af[4], bfr[4];
                #pragma unroll
                for (int mt = 0; mt < 4; ++mt)
                    af[mt] = *(const bf16x8*)&As[s * 4096 + (wm + mt * 16 + lm) * 32 + kq];
                #pragma unroll
                for (int nt = 0; nt < 4; ++nt)
                    bfr[nt] = *(const bf16x8*)&Bs[s * 4096 + (wn + nt * 16 + lm) * 32 + kq];
                #pragma unroll
                for (int mt = 0; mt < 4; ++mt)
                    #pragma unroll
                    for (int nt = 0; nt < 4; ++nt)
                        acc[mt][nt] = __builtin_amdgcn_mfma_f32_16x16x32_bf16(af[mt], bfr[nt], acc[mt][nt], 0, 0, 0);
            }
            __syncthreads();
        }

        #pragma unroll
        for (int mt = 0; mt < 4; ++mt)
            #pragma unroll
            for (int nt = 0; nt < 4; ++nt) {
                int col = ct + wn + nt * 16 + lm;
                float bv = conv_b[col];
                #pragma unroll
                for (int r = 0; r < 4; ++r) {
                    int row = rt + wm + mt * 16 + lq * 4 + r;
                    feats[(size_t)row * 2048 + col] = fmaxf(acc[mt][nt][r] + bv, 0.0f);
                }
            }
    } else {
        // ---------------- gemm64#1: h = relu(gbf @ W1T^T + b1) -------------
        const int t  = bid - 768;
        const int xc = t & 7;
        const int g  = t >> 3;              // 0..63
        const int rt = (g & 15) * 64;
        const int ct = (4 * xc + (g >> 4)) * 64;
        g64_tile<true>(lds, lds + 4096, gbf, W1T, h, b1, rt, ct);
    }
}

// ---- dispatch 3: ahb = a @ h (bf16), normalize folded in, XCD-swizzled ----
__global__ __launch_bounds__(256)
void k_amul(const float* __restrict__ adj, const float* __restrict__ H,
            uint16_t* __restrict__ outp)
{
    __shared__ AmulSM sm;
    int b, i; amul_swizzle(blockIdx.x, b, i);
    amul_body(adj, H, outp, b, i, threadIdx.x, &sm);
}

// ---- dispatch 4: out = ahb @ W2T^T + b2, BK=64, XCD-swizzled --------------
__global__ __launch_bounds__(256)
void k_gemm64(const uint16_t* __restrict__ A, const uint16_t* __restrict__ BT,
              float* __restrict__ C, const float* __restrict__ bias)
{
    __shared__ __align__(16) uint16_t lds[8192];
    const int bid = blockIdx.x;
    const int xc  = bid & 7;
    const int g   = bid >> 3;
    const int rt  = (g & 15) * 64;
    const int ct  = (4 * xc + (g >> 4)) * 64;
    g64_tile<false>(lds, lds + 4096, A, BT, C, bias, rt, ct);
}

// ---- launch ---------------------------------------------------------------

extern "C" void kernel_launch(void* const* d_in, const int* in_sizes, int n_in,
                              void* d_out, int out_size, void* d_ws, size_t ws_size,
                              hipStream_t stream)
{
    const float* x      = (const float*)d_in[0];
    const float* nodes  = (const float*)d_in[1];
    const float* adj    = (const float*)d_in[2];
    const float* conv_w = (const float*)d_in[3];
    const float* conv_b = (const float*)d_in[4];
    const float* W1     = (const float*)d_in[5];
    const float* b1     = (const float*)d_in[6];
    const float* W2     = (const float*)d_in[7];
    const float* b2     = (const float*)d_in[8];
    float* out = (float*)d_out;

    char* ws = (char*)d_ws;
    uint16_t* xpad   = (uint16_t*)(ws);                 // 25,288,704
    uint16_t* wmT    = (uint16_t*)(ws + 25288704);      // 25,165,824
    uint16_t* W1T    = (uint16_t*)(ws + 50454528);      // 8,388,608
    uint16_t* W2T    = (uint16_t*)(ws + 58843136);      // 8,388,608
    uint16_t* gbf    = (uint16_t*)(ws + 67231744);      // 4,194,304  a@nodes (bf16)
    float*    h      = (float*)   (ws + 71426048);      // 8,388,608  relu(gbf@W1+b1)
    uint16_t* ahb    = (uint16_t*)(ws + 79814656);      // 4,194,304  a@h (bf16)

    // d1: everything that depends only on inputs
    k_prep<<<PR_N, 256, 0, stream>>>(x, xpad, conv_w, wmT,
                                     W1, W2, W1T, W2T, adj, nodes, gbf);
    // d2: conv GEMM || gemm64#1 co-scheduled
    k_big<<<1280, 256, 0, stream>>>(xpad, wmT, out, conv_b, gbf, W1T, h, b1);
    // d3: ahb = a @ h
    k_amul<<<1024, 256, 0, stream>>>(adj, h, ahb);
    // d4: out_gcn = ahb @ W2 + b2
    k_gemm64<<<512, 256, 0, stream>>>(ahb, W2T, out + 12582912, b2);
}